// Round 3
// baseline (10794.363 us; speedup 1.0000x reference)
//
#include <hip/hip_runtime.h>
#include <stdint.h>

#define BDIM 256
#define SEQL 128
#define IND 512
#define HID 512
#define NG 2048   // 4*HID
#define KDIM 1024 // IND + HID

__device__ __forceinline__ float sigm(float x) { return 1.0f / (1.0f + __expf(-x)); }

// ---- init: h0,c0 from the zero-input zero-state cell (gates = bias) ----
__global__ void k_init(const float* __restrict__ b_ih, const float* __restrict__ b_hh,
                       float* __restrict__ c, float* __restrict__ A0) {
  int b = blockIdx.x;
  for (int j = threadIdx.x; j < HID; j += blockDim.x) {
    float bi = b_ih[j] + b_hh[j];
    float bg = b_ih[2 * HID + j] + b_hh[2 * HID + j];
    float bo = b_ih[3 * HID + j] + b_hh[3 * HID + j];
    float c0 = sigm(bi) * tanhf(bg);
    float h0 = sigm(bo) * tanhf(c0);
    c[b * HID + j] = c0;
    A0[(size_t)b * KDIM + IND + j] = h0;
  }
}

// ---- per step: attention logits -> softmax -> xi (fp32 into acts buffer) ----
__global__ __launch_bounds__(256) void k_attn(const float* __restrict__ c, const float* __restrict__ Wa,
                                              const float* __restrict__ ba, const float* __restrict__ x,
                                              float* __restrict__ A) {
  __shared__ float sc[HID];
  __shared__ float sl[SEQL];
  int b = blockIdx.x, tid = threadIdx.x;
  sc[tid] = c[b * HID + tid];
  sc[tid + 256] = c[b * HID + tid + 256];
  __syncthreads();
  int wave = tid >> 6, lane = tid & 63;
  for (int si = 0; si < 32; ++si) {
    int s = wave * 32 + si;
    const float* wr = Wa + s * HID;
    float acc = 0.f;
#pragma unroll
    for (int it = 0; it < 8; ++it) {
      int k = lane + it * 64;
      acc += sc[k] * wr[k];
    }
#pragma unroll
    for (int off = 32; off > 0; off >>= 1) acc += __shfl_down(acc, off);
    if (lane == 0) sl[s] = acc + ba[s];
  }
  __syncthreads();
  if (tid < 64) {
    float v0 = sl[tid], v1 = sl[tid + 64];
    float m = fmaxf(v0, v1);
#pragma unroll
    for (int off = 32; off > 0; off >>= 1) m = fmaxf(m, __shfl_xor(m, off));
    float e0 = __expf(v0 - m), e1 = __expf(v1 - m);
    float s2 = e0 + e1;
#pragma unroll
    for (int off = 32; off > 0; off >>= 1) s2 += __shfl_xor(s2, off);
    float inv = 1.f / s2;
    sl[tid] = e0 * inv; sl[tid + 64] = e1 * inv;
  }
  __syncthreads();
  const float* xrow = x + (size_t)b * SEQL * IND;
  float a0 = 0.f, a1 = 0.f;
#pragma unroll 4
  for (int s = 0; s < SEQL; ++s) {
    float w = sl[s];
    float2 v = *(const float2*)(xrow + s * IND + 2 * tid);
    a0 += w * v.x;
    a1 += w * v.y;
  }
  float2 r; r.x = a0; r.y = a1;
  *(float2*)(A + (size_t)b * KDIM + 2 * tid) = r;
}

// ---- per step: fp32 VALU GEMM gates = A @ W'^T + fused cell update ----
// W' row n' = 4*j + g maps to original row g*HID + j of [W_ih | W_hh],
// gathered on the fly (no weight prep, no ws usage for weights).
__global__ __launch_bounds__(256) void k_gates(
    const float* __restrict__ W_ih, const float* __restrict__ W_hh,
    const float* __restrict__ b_ih, const float* __restrict__ b_hh,
    const float* __restrict__ A, float* __restrict__ c,
    float* __restrict__ out, float* __restrict__ Hn, int tstep) {
  __shared__ float sAT[32][68];  // [k][batch-row], padded stride (272 B, 16B-aligned rows)
  __shared__ float sBT[32][68];  // [k][n'-row]
  int tid = threadIdx.x;
  int n0 = blockIdx.x * 64;  // permuted gate-column tile
  int b0 = blockIdx.y * 64;  // batch tile
  int tx = tid & 15, ty = tid >> 4;
  float acc[4][4];
#pragma unroll
  for (int i = 0; i < 4; ++i)
#pragma unroll
    for (int j = 0; j < 4; ++j) acc[i][j] = 0.f;
  int srow = tid >> 2;        // 0..63
  int scol = (tid & 3) * 8;   // 0,8,16,24
  int np = n0 + srow;
  int src = (np & 3) * HID + (np >> 2);
  for (int k0 = 0; k0 < KDIM; k0 += 32) {
    float4 a0v = *(const float4*)(A + (size_t)(b0 + srow) * KDIM + k0 + scol);
    float4 a1v = *(const float4*)(A + (size_t)(b0 + srow) * KDIM + k0 + scol + 4);
    const float* Wsrc = (k0 < IND) ? (W_ih + (size_t)src * IND + k0)
                                   : (W_hh + (size_t)src * HID + (k0 - IND));
    float4 b0v = *(const float4*)(Wsrc + scol);
    float4 b1v = *(const float4*)(Wsrc + scol + 4);
    sAT[scol + 0][srow] = a0v.x; sAT[scol + 1][srow] = a0v.y;
    sAT[scol + 2][srow] = a0v.z; sAT[scol + 3][srow] = a0v.w;
    sAT[scol + 4][srow] = a1v.x; sAT[scol + 5][srow] = a1v.y;
    sAT[scol + 6][srow] = a1v.z; sAT[scol + 7][srow] = a1v.w;
    sBT[scol + 0][srow] = b0v.x; sBT[scol + 1][srow] = b0v.y;
    sBT[scol + 2][srow] = b0v.z; sBT[scol + 3][srow] = b0v.w;
    sBT[scol + 4][srow] = b1v.x; sBT[scol + 5][srow] = b1v.y;
    sBT[scol + 6][srow] = b1v.z; sBT[scol + 7][srow] = b1v.w;
    __syncthreads();
#pragma unroll
    for (int kk = 0; kk < 32; ++kk) {
      float4 av = *(const float4*)(&sAT[kk][ty * 4]);
      float4 bv = *(const float4*)(&sBT[kk][tx * 4]);
      float aa[4] = {av.x, av.y, av.z, av.w};
      float bb[4] = {bv.x, bv.y, bv.z, bv.w};
#pragma unroll
      for (int i = 0; i < 4; ++i)
#pragma unroll
        for (int j = 0; j < 4; ++j) acc[i][j] += aa[i] * bb[j];
    }
    __syncthreads();
  }
  // thread's 4 cols = n' = n0+tx*4+{0,1,2,3} = the 4 gates (i,f,g,o) of hidden jh
  int jh = (n0 >> 2) + tx;
  float bi = b_ih[jh] + b_hh[jh];
  float bf = b_ih[HID + jh] + b_hh[HID + jh];
  float bg = b_ih[2 * HID + jh] + b_hh[2 * HID + jh];
  float bo = b_ih[3 * HID + jh] + b_hh[3 * HID + jh];
#pragma unroll
  for (int i = 0; i < 4; ++i) {
    int b = b0 + ty * 4 + i;
    float ig = sigm(acc[i][0] + bi);
    float fg = sigm(acc[i][1] + bf);
    float gg = tanhf(acc[i][2] + bg);
    float og = sigm(acc[i][3] + bo);
    float co = c[b * HID + jh];
    float cn = fg * co + ig * gg;
    float hv = og * tanhf(cn);
    c[b * HID + jh] = cn;
    out[((size_t)b * SEQL + tstep) * HID + jh] = hv;
    Hn[(size_t)b * KDIM + IND + jh] = hv;
  }
}

extern "C" void kernel_launch(void* const* d_in, const int* in_sizes, int n_in,
                              void* d_out, int out_size, void* d_ws, size_t ws_size,
                              hipStream_t stream) {
  (void)in_sizes; (void)n_in; (void)out_size; (void)ws_size;
  const float* x    = (const float*)d_in[0];
  const float* W_ih = (const float*)d_in[1];
  const float* W_hh = (const float*)d_in[2];
  const float* b_ih = (const float*)d_in[3];
  const float* b_hh = (const float*)d_in[4];
  const float* Wa   = (const float*)d_in[5];
  const float* ba   = (const float*)d_in[6];
  float* out = (float*)d_out;

  // Tiny ws footprint: 2.5 MiB total.
  char* p = (char*)d_ws;
  auto carve = [&](size_t bytes) { char* r = p; p += (bytes + 255) & ~(size_t)255; return r; };
  float* c  = (float*)carve((size_t)BDIM * HID * 4);
  float* A0 = (float*)carve((size_t)BDIM * KDIM * 4);
  float* A1 = (float*)carve((size_t)BDIM * KDIM * 4);

  k_init<<<BDIM, 256, 0, stream>>>(b_ih, b_hh, c, A0);

  for (int t = 0; t < 128; ++t) {
    float* R = (t & 1) ? A1 : A0;  // acts read this step (xi | h)
    float* D = (t & 1) ? A0 : A1;  // h destination (next step's buffer)
    k_attn<<<BDIM, 256, 0, stream>>>(c, Wa, ba, x, R);
    k_gates<<<dim3(32, 4), 256, 0, stream>>>(W_ih, W_hh, b_ih, b_hh, R, c, out, D, t);
  }
}

// Round 7
// 8016.591 us; speedup vs baseline: 1.3465x; 1.3465x over previous
//
#include <hip/hip_runtime.h>
#include <stdint.h>

#define BDIM 256
#define SEQL 128
#define IND 512
#define HID 512
#define KDIM 1024 // IND + HID

__device__ __forceinline__ float sigm(float x) { return 1.0f / (1.0f + __expf(-x)); }

// ---- init: h0,c0 from the zero-input zero-state cell (gates = bias) ----
__global__ void k_init(const float* __restrict__ b_ih, const float* __restrict__ b_hh,
                       float* __restrict__ c, float* __restrict__ A0) {
  int b = blockIdx.x;
  for (int j = threadIdx.x; j < HID; j += blockDim.x) {
    float bi = b_ih[j] + b_hh[j];
    float bg = b_ih[2 * HID + j] + b_hh[2 * HID + j];
    float bo = b_ih[3 * HID + j] + b_hh[3 * HID + j];
    float c0 = sigm(bi) * tanhf(bg);
    float h0 = sigm(bo) * tanhf(c0);
    c[b * HID + j] = c0;
    A0[(size_t)b * KDIM + IND + j] = h0;
  }
}

// ---- per step: attention logits -> softmax -> xi (fp32 into acts buffer) ----
__global__ __launch_bounds__(256) void k_attn(const float* __restrict__ c, const float* __restrict__ Wa,
                                              const float* __restrict__ ba, const float* __restrict__ x,
                                              float* __restrict__ A) {
  __shared__ float sc[HID];
  __shared__ float sl[SEQL];
  __shared__ float sxi[2][HID];
  int b = blockIdx.x, tid = threadIdx.x;
  sc[tid] = c[b * HID + tid];
  sc[tid + 256] = c[b * HID + tid + 256];
  __syncthreads();
  int wave = tid >> 6, lane = tid & 63;
  // logits: 4 waves x 32 rows, shuffle-reduced (R3-proven)
  for (int si = 0; si < 32; ++si) {
    int s = wave * 32 + si;
    const float* wr = Wa + s * HID;
    float acc = 0.f;
#pragma unroll
    for (int it = 0; it < 8; ++it) {
      int k = lane + it * 64;
      acc += sc[k] * wr[k];
    }
#pragma unroll
    for (int off = 32; off > 0; off >>= 1) acc += __shfl_down(acc, off);
    if (lane == 0) sl[s] = acc + ba[s];
  }
  __syncthreads();
  if (tid < 64) {
    float v0 = sl[tid], v1 = sl[tid + 64];
    float m = fmaxf(v0, v1);
#pragma unroll
    for (int off = 32; off > 0; off >>= 1) m = fmaxf(m, __shfl_xor(m, off));
    float e0 = __expf(v0 - m), e1 = __expf(v1 - m);
    float s2 = e0 + e1;
#pragma unroll
    for (int off = 32; off > 0; off >>= 1) s2 += __shfl_xor(s2, off);
    float inv = 1.f / s2;
    sl[tid] = e0 * inv; sl[tid + 64] = e1 * inv;
  }
  __syncthreads();
  // xi: float4 per thread, seq split into two halves across the block
  int cix = tid & 127;        // column quad 0..127 -> cols 4*cix..4*cix+3
  int ph = tid >> 7;          // seq half 0/1
  const float* xrow = x + (size_t)b * SEQL * IND + (size_t)ph * 64 * IND;
  float4 a = {0.f, 0.f, 0.f, 0.f};
#pragma unroll 4
  for (int s = 0; s < 64; ++s) {
    float w = sl[ph * 64 + s];
    float4 v = *(const float4*)(xrow + s * IND + 4 * cix);
    a.x += w * v.x; a.y += w * v.y; a.z += w * v.z; a.w += w * v.w;
  }
  *(float4*)(&sxi[ph][4 * cix]) = a;
  __syncthreads();
  float2 r;
  r.x = sxi[0][2 * tid] + sxi[1][2 * tid];
  r.y = sxi[0][2 * tid + 1] + sxi[1][2 * tid + 1];
  *(float2*)(A + (size_t)b * KDIM + 2 * tid) = r;
}

// ---- per step: fp32 GEMM gates = A @ W'^T + fused cell update ----
// 32(batch) x 64(n') tile, grid (32,8)=256 blocks, K-chunk 64, reg-prefetch.
// W' row n' = 4*j + gate maps to original row gate*HID + j of [W_ih | W_hh].
__global__ __launch_bounds__(256) void k_gates(
    const float* __restrict__ W_ih, const float* __restrict__ W_hh,
    const float* __restrict__ b_ih, const float* __restrict__ b_hh,
    const float* __restrict__ A, float* __restrict__ c,
    float* __restrict__ out, float* __restrict__ Hn, int tstep) {
  __shared__ float sAT[64][34];  // [k][batch-row], pad->2-way max on reads
  __shared__ float sBT[64][68];  // [k][n'-row]
  int tid = threadIdx.x;
  int n0 = blockIdx.x * 64;   // permuted gate-column tile
  int b0 = blockIdx.y * 32;   // batch tile
  int tx = tid & 15, ty = tid >> 4;
  float acc[2][4] = {{0.f, 0.f, 0.f, 0.f}, {0.f, 0.f, 0.f, 0.f}};

  int arow = tid >> 3;          // 0..31  (batch row within tile)
  int acol = (tid & 7) * 8;     // k-offset 0..56
  int brow = tid >> 2;          // 0..63  (n' row within tile)
  int bcol = (tid & 3) * 16;    // k-offset 0,16,32,48
  int np = n0 + brow;
  int src = (np & 3) * HID + (np >> 2);  // original W row (torch gate order)
  const float* Arow = A + (size_t)(b0 + arow) * KDIM;

  float4 pa0, pa1, pw0, pw1, pw2, pw3;
  {
    pa0 = *(const float4*)(Arow + acol);
    pa1 = *(const float4*)(Arow + acol + 4);
    const float* Wsrc = W_ih + (size_t)src * IND;
    pw0 = *(const float4*)(Wsrc + bcol);
    pw1 = *(const float4*)(Wsrc + bcol + 4);
    pw2 = *(const float4*)(Wsrc + bcol + 8);
    pw3 = *(const float4*)(Wsrc + bcol + 12);
  }
  for (int k0 = 0; k0 < KDIM; k0 += 64) {
    // stores from prefetched regs (transposed)
    sAT[acol + 0][arow] = pa0.x; sAT[acol + 1][arow] = pa0.y;
    sAT[acol + 2][arow] = pa0.z; sAT[acol + 3][arow] = pa0.w;
    sAT[acol + 4][arow] = pa1.x; sAT[acol + 5][arow] = pa1.y;
    sAT[acol + 6][arow] = pa1.z; sAT[acol + 7][arow] = pa1.w;
    sBT[bcol + 0][brow] = pw0.x;  sBT[bcol + 1][brow] = pw0.y;
    sBT[bcol + 2][brow] = pw0.z;  sBT[bcol + 3][brow] = pw0.w;
    sBT[bcol + 4][brow] = pw1.x;  sBT[bcol + 5][brow] = pw1.y;
    sBT[bcol + 6][brow] = pw1.z;  sBT[bcol + 7][brow] = pw1.w;
    sBT[bcol + 8][brow] = pw2.x;  sBT[bcol + 9][brow] = pw2.y;
    sBT[bcol + 10][brow] = pw2.z; sBT[bcol + 11][brow] = pw2.w;
    sBT[bcol + 12][brow] = pw3.x; sBT[bcol + 13][brow] = pw3.y;
    sBT[bcol + 14][brow] = pw3.z; sBT[bcol + 15][brow] = pw3.w;
    __syncthreads();
    // prefetch next chunk (global loads in flight under the FMA loop)
    int kn = k0 + 64;
    if (kn < KDIM) {
      pa0 = *(const float4*)(Arow + kn + acol);
      pa1 = *(const float4*)(Arow + kn + acol + 4);
      const float* Wsrc = (kn < IND) ? (W_ih + (size_t)src * IND + kn)
                                     : (W_hh + (size_t)src * HID + (kn - IND));
      pw0 = *(const float4*)(Wsrc + bcol);
      pw1 = *(const float4*)(Wsrc + bcol + 4);
      pw2 = *(const float4*)(Wsrc + bcol + 8);
      pw3 = *(const float4*)(Wsrc + bcol + 12);
    }
#pragma unroll
    for (int kk = 0; kk < 64; ++kk) {
      float2 av = *(const float2*)(&sAT[kk][ty * 2]);
      float4 bv = *(const float4*)(&sBT[kk][tx * 4]);
      acc[0][0] += av.x * bv.x; acc[0][1] += av.x * bv.y;
      acc[0][2] += av.x * bv.z; acc[0][3] += av.x * bv.w;
      acc[1][0] += av.y * bv.x; acc[1][1] += av.y * bv.y;
      acc[1][2] += av.y * bv.z; acc[1][3] += av.y * bv.w;
    }
    __syncthreads();
  }
  // epilogue: thread owns 2 batches x all 4 gates of hidden jh (R3-proven map)
  int jh = (n0 >> 2) + tx;
  float bi = b_ih[jh] + b_hh[jh];
  float bf = b_ih[HID + jh] + b_hh[HID + jh];
  float bg = b_ih[2 * HID + jh] + b_hh[2 * HID + jh];
  float bo = b_ih[3 * HID + jh] + b_hh[3 * HID + jh];
#pragma unroll
  for (int i = 0; i < 2; ++i) {
    int b = b0 + ty * 2 + i;
    float ig = sigm(acc[i][0] + bi);
    float fg = sigm(acc[i][1] + bf);
    float gg = tanhf(acc[i][2] + bg);
    float og = sigm(acc[i][3] + bo);
    float co = c[b * HID + jh];
    float cn = fg * co + ig * gg;
    float hv = og * tanhf(cn);
    c[b * HID + jh] = cn;
    out[((size_t)b * SEQL + tstep) * HID + jh] = hv;
    Hn[(size_t)b * KDIM + IND + jh] = hv;
  }
}

extern "C" void kernel_launch(void* const* d_in, const int* in_sizes, int n_in,
                              void* d_out, int out_size, void* d_ws, size_t ws_size,
                              hipStream_t stream) {
  (void)in_sizes; (void)n_in; (void)out_size; (void)ws_size;
  const float* x    = (const float*)d_in[0];
  const float* W_ih = (const float*)d_in[1];
  const float* W_hh = (const float*)d_in[2];
  const float* b_ih = (const float*)d_in[3];
  const float* b_hh = (const float*)d_in[4];
  const float* Wa   = (const float*)d_in[5];
  const float* ba   = (const float*)d_in[6];
  float* out = (float*)d_out;

  // ws footprint: 2.5 MiB (proven-good R3 layout).
  char* p = (char*)d_ws;
  auto carve = [&](size_t bytes) { char* r = p; p += (bytes + 255) & ~(size_t)255; return r; };
  float* c  = (float*)carve((size_t)BDIM * HID * 4);
  float* A0 = (float*)carve((size_t)BDIM * KDIM * 4);
  float* A1 = (float*)carve((size_t)BDIM * KDIM * 4);

  k_init<<<BDIM, 256, 0, stream>>>(b_ih, b_hh, c, A0);

  for (int t = 0; t < 128; ++t) {
    float* R = (t & 1) ? A1 : A0;  // acts read this step (xi | h)
    float* D = (t & 1) ? A0 : A1;  // h destination (next step's buffer)
    k_attn<<<BDIM, 256, 0, stream>>>(c, Wa, ba, x, R);
    k_gates<<<dim3(32, 8), 256, 0, stream>>>(W_ih, W_hh, b_ih, b_hh, R,
                                             c, out, D, t);
  }
}